// Round 3
// baseline (1850.602 us; speedup 1.0000x reference)
//
#include <hip/hip_runtime.h>

#define BATCH 8
#define NPTS 4096
#define KSAMP 1024
#define KNEI 64
#define OUTC 131   // 3 xyz + 128 feat

typedef float v2f __attribute__((ext_vector_type(2)));
typedef float v4f __attribute__((ext_vector_type(4)));

// ---------------------------------------------------------------------------
// Packed fp32 helpers (CDNA2+ VOP3P). Per-half semantics are exactly IEEE
// v_add/v_mul/v_fma on fp32, so results are bit-identical to scalar code.
// ---------------------------------------------------------------------------
__device__ __forceinline__ v2f pk_add(v2f a, v2f b) {
    v2f d; asm("v_pk_add_f32 %0, %1, %2" : "=v"(d) : "v"(a), "v"(b)); return d;
}
__device__ __forceinline__ v2f pk_mul(v2f a, v2f b) {
    v2f d; asm("v_pk_mul_f32 %0, %1, %2" : "=v"(d) : "v"(a), "v"(b)); return d;
}
__device__ __forceinline__ v2f pk_fma(v2f a, v2f b, v2f c) {
    v2f d; asm("v_pk_fma_f32 %0, %1, %2, %3" : "=v"(d) : "v"(a), "v"(b), "v"(c)); return d;
}

// ---------------------------------------------------------------------------
// DPP wave64 reductions (verified in R2). Result valid in lane 63.
// ---------------------------------------------------------------------------
__device__ __forceinline__ unsigned long long umax64(unsigned long long a,
                                                     unsigned long long b)
{
    return a > b ? a : b;
}

#define DPP_U64_STEP(v, CTRL)                                                  \
    {                                                                          \
        int _lo = __builtin_amdgcn_update_dpp(0, (int)(unsigned)(v), (CTRL),   \
                                              0xF, 0xF, true);                 \
        int _hi = __builtin_amdgcn_update_dpp(0, (int)((v) >> 32), (CTRL),     \
                                              0xF, 0xF, true);                 \
        unsigned long long _o =                                                \
            ((unsigned long long)(unsigned)_hi << 32) | (unsigned)_lo;         \
        (v) = umax64((v), _o);                                                 \
    }

__device__ __forceinline__ unsigned long long wave_umax64(unsigned long long v)
{
    DPP_U64_STEP(v, 0x111)  // row_shr:1
    DPP_U64_STEP(v, 0x112)  // row_shr:2
    DPP_U64_STEP(v, 0x114)  // row_shr:4
    DPP_U64_STEP(v, 0x118)  // row_shr:8
    DPP_U64_STEP(v, 0x142)  // row_bcast:15
    DPP_U64_STEP(v, 0x143)  // row_bcast:31
    return v;
}

#define DPP_F32MAX_STEP(v, CTRL)                                               \
    {                                                                          \
        int _s = __builtin_amdgcn_update_dpp(0, __float_as_int(v), (CTRL),     \
                                             0xF, 0xF, true);                  \
        (v) = fmaxf((v), __int_as_float(_s));                                  \
    }

__device__ __forceinline__ float wave_fmax_nonneg(float v)
{
    DPP_F32MAX_STEP(v, 0x111)
    DPP_F32MAX_STEP(v, 0x112)
    DPP_F32MAX_STEP(v, 0x114)
    DPP_F32MAX_STEP(v, 0x118)
    DPP_F32MAX_STEP(v, 0x142)
    DPP_F32MAX_STEP(v, 0x143)
    return v;
}

// ---------------------------------------------------------------------------
// Kernel 1: farthest point sampling. 256 threads/batch (1 wave/SIMD),
// 16 pts/thread. v_pk_* distance update (bit-identical to scalar), float
// argmax tree with hoisted index registers (strict '>' = exact lowest-index
// tie-break), one u64 pack per wave, DPP reduce, single-barrier exchange.
// ---------------------------------------------------------------------------
#define FPS_T 256
#define FPS_PPT 16

__global__ __launch_bounds__(FPS_T) void fps_kernel(const float* __restrict__ pts,
                                                    float* __restrict__ out)
{
    const int b = blockIdx.x;
    const int t = threadIdx.x;
    const float* p = pts + (size_t)b * NPTS * 3;

    __shared__ float lx[NPTS], ly[NPTS], lz[NPTS];
    __shared__ unsigned long long cand[2][4];

    v2f pxp[8], pyp[8], pzp[8], mdp[8];
    int idxr[16];
#pragma unroll
    for (int i = 0; i < FPS_PPT; ++i) {
        const int n = t * FPS_PPT + i;
        const float x = p[n * 3 + 0];
        const float y = p[n * 3 + 1];
        const float z = p[n * 3 + 2];
        pxp[i >> 1][i & 1] = x;
        pyp[i >> 1][i & 1] = y;
        pzp[i >> 1][i & 1] = z;
        mdp[i >> 1][i & 1] = 1e10f;    // reference 'big'
        lx[n] = x; ly[n] = y; lz[n] = z;
        idxr[i] = n;                   // hoisted: loop-invariant index regs
    }
    if (t == 0) {
        float* o = out + (size_t)b * KSAMP * OUTC;
        o[0] = p[0]; o[1] = p[1]; o[2] = p[2];   // first selected = index 0
    }
    __syncthreads();

    const int wave = t >> 6;
    const int lane = t & 63;
    float qx = lx[0], qy = ly[0], qz = lz[0];

#define MD(i) ((i) & 1 ? mdp[(i) >> 1].y : mdp[(i) >> 1].x)

    for (int s = 1; s < KSAMP; ++s) {
        // negated query broadcast pairs: a + (-q) == a - q exactly (IEEE)
        const float nqx = -qx, nqy = -qy, nqz = -qz;
        const v2f nqx2 = {nqx, nqx}, nqy2 = {nqy, nqy}, nqz2 = {nqz, nqz};

        // min-dist update: same op sequence as verified scalar kernel
        // (sub, sub, sub, mul, fma, fma, min) but 2 points per instruction
#pragma unroll
        for (int j = 0; j < 8; ++j) {
            v2f dx = pk_add(pxp[j], nqx2);
            v2f dy = pk_add(pyp[j], nqy2);
            v2f dz = pk_add(pzp[j], nqz2);
            v2f d  = pk_fma(dz, dz, pk_fma(dy, dy, pk_mul(dx, dx)));
            mdp[j].x = fminf(mdp[j].x, d.x);
            mdp[j].y = fminf(mdp[j].y, d.y);
        }

        // local float argmax tree; later entry challenges earlier with strict
        // '>' so ties keep the lowest index (jnp.argmax rule), exactly
        float tv[8]; int ti[8];
#pragma unroll
        for (int i = 0; i < 8; ++i) {
            const float a = MD(i), c = MD(i + 8);
            const bool g = c > a;
            tv[i] = g ? c : a;
            ti[i] = g ? idxr[i + 8] : idxr[i];
        }
#pragma unroll
        for (int i = 0; i < 4; ++i) {
            const bool g = tv[i + 4] > tv[i];
            tv[i] = g ? tv[i + 4] : tv[i];
            ti[i] = g ? ti[i + 4] : ti[i];
        }
#pragma unroll
        for (int i = 0; i < 2; ++i) {
            const bool g = tv[i + 2] > tv[i];
            tv[i] = g ? tv[i + 2] : tv[i];
            ti[i] = g ? ti[i + 2] : ti[i];
        }
        const bool g0 = tv[1] > tv[0];
        const float bv = g0 ? tv[1] : tv[0];
        const int   bi = g0 ? ti[1] : ti[0];

        // pack once, DPP-reduce across the wave (exact tie-break via idx bits)
        unsigned long long key =
            ((unsigned long long)__float_as_uint(bv) << 32) | (unsigned)(4095 - bi);
        key = wave_umax64(key);
        const int par = s & 1;
        if (lane == 63) cand[par][wave] = key;
        __syncthreads();

        const unsigned long long g =
            umax64(umax64(cand[par][0], cand[par][1]),
                   umax64(cand[par][2], cand[par][3]));
        const int cur = 4095 - (int)(g & 0xffffffffu);

        qx = lx[cur]; qy = ly[cur]; qz = lz[cur];
        if (t == 0) {
            float* o = out + ((size_t)b * KSAMP + s) * OUTC;
            o[0] = qx; o[1] = qy; o[2] = qz;
        }
    }
#undef MD
}

// ---------------------------------------------------------------------------
// Kernel 2: fused ball-query + 3-layer MLP + neighbor max-pool.
// 4 waves (queries) per block. Weights staged in LDS (54 KB -> 3 blocks/CU,
// 3 waves/SIMD) and consumed as broadcast ds_read_b128 (uniform address, no
// bank conflicts) -- removes the s_load prefetch stalls seen in R1/R2.
// FMA accumulation order per output is unchanged from the verified kernel.
// ---------------------------------------------------------------------------
__global__ __launch_bounds__(256, 3) void bqmlp_kernel(
    const float* __restrict__ pts,
    const float* __restrict__ w0, const float* __restrict__ b0,
    const float* __restrict__ w1, const float* __restrict__ b1,
    const float* __restrict__ w2, const float* __restrict__ b2,
    float* __restrict__ out)
{
    const int t    = threadIdx.x;
    const int wv   = t >> 6;
    const int lane = t & 63;
    const int q    = blockIdx.x * 4 + wv;     // 0..8191
    const int bb   = q >> 10;
    const float* p = pts + (size_t)bb * NPTS * 3;
    float* orow    = out + (size_t)q * OUTC;

    __shared__ v4f sw0[48];        // w0: [3][64]
    __shared__ v4f sb0[16];
    __shared__ v4f sw1[1024];      // w1: [64][64]
    __shared__ v4f sb1[16];
    __shared__ v4f sw2[2048];      // w2: [64][128]
    __shared__ v4f sb2[32];
    __shared__ float snx[4][KNEI], sny[4][KNEI], snz[4][KNEI];

    // ---- stage weights (coalesced float4 loads) ----
    {
        const v4f* g1 = (const v4f*)w1;
#pragma unroll
        for (int i = 0; i < 4; ++i) sw1[t + i * 256] = g1[t + i * 256];
        const v4f* g2 = (const v4f*)w2;
#pragma unroll
        for (int i = 0; i < 8; ++i) sw2[t + i * 256] = g2[t + i * 256];
        if (t < 48) sw0[t] = ((const v4f*)w0)[t];
        if (t < 16) sb0[t] = ((const v4f*)b0)[t];
        if (t < 16) sb1[t] = ((const v4f*)b1)[t];
        if (t < 32) sb2[t] = ((const v4f*)b2)[t];
    }

    // ---- ball query (per wave, no block barrier inside) ----
    const float qx = orow[0], qy = orow[1], qz = orow[2];
    const float RR = 0.04f;
    const float q2 = __fadd_rn(__fadd_rn(__fmul_rn(qx, qx), __fmul_rn(qy, qy)),
                               __fmul_rn(qz, qz));

    snx[wv][lane] = 0.0f; sny[wv][lane] = 0.0f; snz[wv][lane] = 0.0f;

    int total = 0;
    for (int c = 0; c < NPTS / 64 && total < KNEI; ++c) {
        const int n = c * 64 + lane;
        const float x = p[n * 3 + 0];
        const float y = p[n * 3 + 1];
        const float z = p[n * 3 + 2];
        const float p2  = __fadd_rn(__fadd_rn(__fmul_rn(x, x), __fmul_rn(y, y)),
                                    __fmul_rn(z, z));
        const float dot = __fadd_rn(__fadd_rn(__fmul_rn(qx, x), __fmul_rn(qy, y)),
                                    __fmul_rn(qz, z));
        const float d2  = __fsub_rn(__fadd_rn(q2, p2), __fmul_rn(2.0f, dot));
        const bool valid = d2 < RR;
        const unsigned long long mask = __ballot(valid);
        const int pos = total + (int)__popcll(mask & ((1ull << lane) - 1ull));
        if (valid && pos < KNEI) { snx[wv][pos] = x; sny[wv][pos] = y; snz[wv][pos] = z; }
        total += (int)__popcll(mask);
    }

    __syncthreads();   // staging + neighbor writes visible

    const float x = snx[wv][lane], y = sny[wv][lane], z = snz[wv][lane];

    // ---- layer 1: 3 -> 64 ----
    float h0[64];
#pragma unroll
    for (int j4 = 0; j4 < 16; ++j4) {
        const v4f wx = sw0[j4], wy = sw0[16 + j4], wz = sw0[32 + j4], bv = sb0[j4];
#pragma unroll
        for (int c = 0; c < 4; ++c) {
            float a = fmaf(x, wx[c], fmaf(y, wy[c], fmaf(z, wz[c], bv[c])));
            h0[j4 * 4 + c] = fmaxf(a, 0.0f);
        }
    }

    // ---- layer 2: 64 -> 64 ----
    float h1[64];
#pragma unroll
    for (int jb = 0; jb < 4; ++jb) {
        float acc[16];
#pragma unroll
        for (int i4 = 0; i4 < 4; ++i4) {
            const v4f bv = sb1[jb * 4 + i4];
#pragma unroll
            for (int c = 0; c < 4; ++c) acc[i4 * 4 + c] = bv[c];
        }
#pragma unroll
        for (int k = 0; k < 64; ++k) {
            const float hk = h0[k];
            const v4f wA = sw1[k * 16 + jb * 4 + 0];
            const v4f wB = sw1[k * 16 + jb * 4 + 1];
            const v4f wC = sw1[k * 16 + jb * 4 + 2];
            const v4f wD = sw1[k * 16 + jb * 4 + 3];
#pragma unroll
            for (int c = 0; c < 4; ++c) {
                acc[c]      = fmaf(hk, wA[c], acc[c]);
                acc[4 + c]  = fmaf(hk, wB[c], acc[4 + c]);
                acc[8 + c]  = fmaf(hk, wC[c], acc[8 + c]);
                acc[12 + c] = fmaf(hk, wD[c], acc[12 + c]);
            }
        }
#pragma unroll
        for (int i = 0; i < 16; ++i) h1[jb * 16 + i] = fmaxf(acc[i], 0.0f);
    }

    // ---- layer 3: 64 -> 128, fused relu + neighbor max ----
#pragma unroll
    for (int jb = 0; jb < 8; ++jb) {
        float acc[16];
#pragma unroll
        for (int i4 = 0; i4 < 4; ++i4) {
            const v4f bv = sb2[jb * 4 + i4];
#pragma unroll
            for (int c = 0; c < 4; ++c) acc[i4 * 4 + c] = bv[c];
        }
#pragma unroll
        for (int k = 0; k < 64; ++k) {
            const float hk = h1[k];
            const v4f wA = sw2[k * 32 + jb * 4 + 0];
            const v4f wB = sw2[k * 32 + jb * 4 + 1];
            const v4f wC = sw2[k * 32 + jb * 4 + 2];
            const v4f wD = sw2[k * 32 + jb * 4 + 3];
#pragma unroll
            for (int c = 0; c < 4; ++c) {
                acc[c]      = fmaf(hk, wA[c], acc[c]);
                acc[4 + c]  = fmaf(hk, wB[c], acc[4 + c]);
                acc[8 + c]  = fmaf(hk, wC[c], acc[8 + c]);
                acc[12 + c] = fmaf(hk, wD[c], acc[12 + c]);
            }
        }
#pragma unroll
        for (int i = 0; i < 16; ++i) {
            float v = fmaxf(acc[i], 0.0f);   // relu before pooling
            acc[i] = wave_fmax_nonneg(v);    // valid in lane 63
        }
        if (lane == 63) {
#pragma unroll
            for (int i = 0; i < 16; ++i) orow[3 + jb * 16 + i] = acc[i];
        }
    }
}

extern "C" void kernel_launch(void* const* d_in, const int* in_sizes, int n_in,
                              void* d_out, int out_size, void* d_ws, size_t ws_size,
                              hipStream_t stream)
{
    (void)in_sizes; (void)n_in; (void)out_size; (void)d_ws; (void)ws_size;
    const float* pts = (const float*)d_in[0];
    const float* w0  = (const float*)d_in[1];
    const float* b0  = (const float*)d_in[2];
    const float* w1  = (const float*)d_in[3];
    const float* b1  = (const float*)d_in[4];
    const float* w2  = (const float*)d_in[5];
    const float* b2  = (const float*)d_in[6];
    float* out = (float*)d_out;

    hipLaunchKernelGGL(fps_kernel, dim3(BATCH), dim3(FPS_T), 0, stream, pts, out);
    hipLaunchKernelGGL(bqmlp_kernel, dim3(BATCH * KSAMP / 4), dim3(256), 0, stream,
                       pts, w0, b0, w1, b1, w2, b2, out);
}

// Round 4
// 1250.479 us; speedup vs baseline: 1.4799x; 1.4799x over previous
//
#include <hip/hip_runtime.h>

#define BATCH 8
#define NPTS 4096
#define KSAMP 1024
#define KNEI 64
#define OUTC 131   // 3 xyz + 128 feat

// ---------------------------------------------------------------------------
// DPP wave64 reductions (verified R2/R3). Result valid in lane 63.
// bound_ctrl=true zero-fills; identity for max over nonneg keys/values.
// ---------------------------------------------------------------------------
__device__ __forceinline__ unsigned long long umax64(unsigned long long a,
                                                     unsigned long long b)
{
    return a > b ? a : b;
}

#define DPP_U64_STEP(v, CTRL)                                                  \
    {                                                                          \
        int _lo = __builtin_amdgcn_update_dpp(0, (int)(unsigned)(v), (CTRL),   \
                                              0xF, 0xF, true);                 \
        int _hi = __builtin_amdgcn_update_dpp(0, (int)((v) >> 32), (CTRL),     \
                                              0xF, 0xF, true);                 \
        unsigned long long _o =                                                \
            ((unsigned long long)(unsigned)_hi << 32) | (unsigned)_lo;         \
        (v) = umax64((v), _o);                                                 \
    }

__device__ __forceinline__ unsigned long long wave_umax64(unsigned long long v)
{
    DPP_U64_STEP(v, 0x111)  // row_shr:1
    DPP_U64_STEP(v, 0x112)  // row_shr:2
    DPP_U64_STEP(v, 0x114)  // row_shr:4
    DPP_U64_STEP(v, 0x118)  // row_shr:8
    DPP_U64_STEP(v, 0x142)  // row_bcast:15
    DPP_U64_STEP(v, 0x143)  // row_bcast:31
    return v;
}

#define DPP_F32MAX_STEP(v, CTRL)                                               \
    {                                                                          \
        int _s = __builtin_amdgcn_update_dpp(0, __float_as_int(v), (CTRL),     \
                                             0xF, 0xF, true);                  \
        (v) = fmaxf((v), __int_as_float(_s));                                  \
    }

__device__ __forceinline__ float wave_fmax_nonneg(float v)
{
    DPP_F32MAX_STEP(v, 0x111)
    DPP_F32MAX_STEP(v, 0x112)
    DPP_F32MAX_STEP(v, 0x114)
    DPP_F32MAX_STEP(v, 0x118)
    DPP_F32MAX_STEP(v, 0x142)
    DPP_F32MAX_STEP(v, 0x143)
    return v;
}

// ---------------------------------------------------------------------------
// Kernel 1: farthest point sampling — VERBATIM revert to the R2 kernel that
// measured 629 us (the R3 pk-asm variant regressed 2.35x). 256 threads per
// batch, 16 pts/thread, u64-packed candidates, DPP wave reduce, one
// parity-double-buffered barrier per iteration.
// ---------------------------------------------------------------------------
#define FPS_T 256
#define FPS_PPT 16

__global__ __launch_bounds__(FPS_T) void fps_kernel(const float* __restrict__ pts,
                                                    float* __restrict__ out)
{
    const int b = blockIdx.x;
    const int t = threadIdx.x;
    const float* p = pts + (size_t)b * NPTS * 3;

    __shared__ float lx[NPTS], ly[NPTS], lz[NPTS];
    __shared__ unsigned long long cand[2][4];

    float px[FPS_PPT], py[FPS_PPT], pz[FPS_PPT], md[FPS_PPT];
#pragma unroll
    for (int i = 0; i < FPS_PPT; ++i) {
        const int n = t * FPS_PPT + i;
        px[i] = p[n * 3 + 0];
        py[i] = p[n * 3 + 1];
        pz[i] = p[n * 3 + 2];
        lx[n] = px[i]; ly[n] = py[i]; lz[n] = pz[i];
        md[i] = 1e10f;                   // reference 'big'
    }
    if (t == 0) {
        float* o = out + (size_t)b * KSAMP * OUTC;
        o[0] = p[0]; o[1] = p[1]; o[2] = p[2];   // first selected = index 0
    }
    __syncthreads();

    const int wave = t >> 6;
    const int lane = t & 63;
    int cur = 0;

    for (int s = 1; s < KSAMP; ++s) {
        const float qx = lx[cur], qy = ly[cur], qz = lz[cur];

#pragma unroll
        for (int i = 0; i < FPS_PPT; ++i) {
            float dx = px[i] - qx, dy = py[i] - qy, dz = pz[i] - qz;
            float d = dx * dx + dy * dy + dz * dz;
            md[i] = fminf(md[i], d);
        }

        unsigned long long c[FPS_PPT];
#pragma unroll
        for (int i = 0; i < FPS_PPT; ++i)
            c[i] = ((unsigned long long)__float_as_uint(md[i]) << 32)
                 | (unsigned)(4095 - (t * FPS_PPT + i));
#pragma unroll
        for (int i = 0; i < 8; ++i) c[i] = umax64(c[i], c[i + 8]);
#pragma unroll
        for (int i = 0; i < 4; ++i) c[i] = umax64(c[i], c[i + 4]);
        c[0] = umax64(c[0], c[2]);
        c[1] = umax64(c[1], c[3]);
        unsigned long long best = umax64(c[0], c[1]);

        best = wave_umax64(best);
        const int par = s & 1;
        if (lane == 63) cand[par][wave] = best;
        __syncthreads();

        unsigned long long g = umax64(umax64(cand[par][0], cand[par][1]),
                                      umax64(cand[par][2], cand[par][3]));
        cur = 4095 - (int)(g & 0xffffffffu);

        if (t == 0) {
            float* o = out + ((size_t)b * KSAMP + s) * OUTC;
            o[0] = lx[cur]; o[1] = ly[cur]; o[2] = lz[cur];
        }
    }
}

// ---------------------------------------------------------------------------
// PROBE (experiment, results go to d_ws only; launched before the real
// kernels so its output is irrelevant to correctness). Same structure as
// fps_kernel but 256 iterations and NO cross-wave exchange: the barrier +
// LDS candidate round-trip is replaced by v_readlane of the wave-local
// winner. Comparing (probe_dur/256) vs (fps_dur/1023) isolates the cost of
// the barrier+exchange stage and aims the next FPS optimization.
// ---------------------------------------------------------------------------
__global__ __launch_bounds__(FPS_T) void fps_probe(const float* __restrict__ pts,
                                                   unsigned long long* __restrict__ ws)
{
    const int b = blockIdx.x;
    const int t = threadIdx.x;
    const float* p = pts + (size_t)b * NPTS * 3;

    __shared__ float lx[NPTS], ly[NPTS], lz[NPTS];

    float px[FPS_PPT], py[FPS_PPT], pz[FPS_PPT], md[FPS_PPT];
#pragma unroll
    for (int i = 0; i < FPS_PPT; ++i) {
        const int n = t * FPS_PPT + i;
        px[i] = p[n * 3 + 0];
        py[i] = p[n * 3 + 1];
        pz[i] = p[n * 3 + 2];
        lx[n] = px[i]; ly[n] = py[i]; lz[n] = pz[i];
        md[i] = 1e10f;
    }
    __syncthreads();

    int cur = 0;
    unsigned acc = 0;

    for (int s = 1; s < 257; ++s) {
        const float qx = lx[cur], qy = ly[cur], qz = lz[cur];

#pragma unroll
        for (int i = 0; i < FPS_PPT; ++i) {
            float dx = px[i] - qx, dy = py[i] - qy, dz = pz[i] - qz;
            float d = dx * dx + dy * dy + dz * dz;
            md[i] = fminf(md[i], d);
        }

        unsigned long long c[FPS_PPT];
#pragma unroll
        for (int i = 0; i < FPS_PPT; ++i)
            c[i] = ((unsigned long long)__float_as_uint(md[i]) << 32)
                 | (unsigned)(4095 - (t * FPS_PPT + i));
#pragma unroll
        for (int i = 0; i < 8; ++i) c[i] = umax64(c[i], c[i + 8]);
#pragma unroll
        for (int i = 0; i < 4; ++i) c[i] = umax64(c[i], c[i + 4]);
        c[0] = umax64(c[0], c[2]);
        c[1] = umax64(c[1], c[3]);
        unsigned long long best = umax64(c[0], c[1]);

        best = wave_umax64(best);
        // wave-local winner broadcast (replaces barrier + LDS exchange)
        const unsigned lo = (unsigned)__builtin_amdgcn_readlane((int)(unsigned)best, 63);
        cur = 4095 - (int)lo;
        acc ^= (unsigned)cur;
    }
    if (t == 0) ws[b] = acc;   // keep everything live
}

// ---------------------------------------------------------------------------
// Kernel 2: fused ball-query + 3-layer MLP + neighbor max-pool.
// 4 query-waves per 256-thread block (raises resident waves/CU past the
// small-workgroup dispatch cap). Weights read straight from global with
// uniform addresses -> scalar s_load through K$, shared across all waves;
// VALU stream stays pure v_fmac_f32. FMA accumulation order per output is
// identical to the verified R1/R2 kernel (k ascending, fmaf chain).
// ---------------------------------------------------------------------------
__global__ __launch_bounds__(256, 6) void bqmlp_kernel(
    const float* __restrict__ pts,
    const float* __restrict__ w0, const float* __restrict__ b0,
    const float* __restrict__ w1, const float* __restrict__ b1,
    const float* __restrict__ w2, const float* __restrict__ b2,
    float* __restrict__ out)
{
    const int t    = threadIdx.x;
    const int wv   = t >> 6;
    const int lane = t & 63;
    const int q    = blockIdx.x * 4 + wv;     // 0..8191
    const int bb   = q >> 10;
    const float* p = pts + (size_t)bb * NPTS * 3;
    float* orow    = out + (size_t)q * OUTC;

    __shared__ float snx[4][KNEI], sny[4][KNEI], snz[4][KNEI];

    // ---- ball query (per wave; no barrier inside the chunk loop) ----
    const float qx = orow[0], qy = orow[1], qz = orow[2];
    const float RR = 0.04f;
    const float q2 = __fadd_rn(__fadd_rn(__fmul_rn(qx, qx), __fmul_rn(qy, qy)),
                               __fmul_rn(qz, qz));

    snx[wv][lane] = 0.0f; sny[wv][lane] = 0.0f; snz[wv][lane] = 0.0f;

    int total = 0;
    for (int c = 0; c < NPTS / 64 && total < KNEI; ++c) {
        const int n = c * 64 + lane;
        const float x = p[n * 3 + 0];
        const float y = p[n * 3 + 1];
        const float z = p[n * 3 + 2];
        const float p2  = __fadd_rn(__fadd_rn(__fmul_rn(x, x), __fmul_rn(y, y)),
                                    __fmul_rn(z, z));
        const float dot = __fadd_rn(__fadd_rn(__fmul_rn(qx, x), __fmul_rn(qy, y)),
                                    __fmul_rn(qz, z));
        const float d2  = __fsub_rn(__fadd_rn(q2, p2), __fmul_rn(2.0f, dot));
        const bool valid = d2 < RR;
        const unsigned long long mask = __ballot(valid);
        const int pos = total + (int)__popcll(mask & ((1ull << lane) - 1ull));
        if (valid && pos < KNEI) { snx[wv][pos] = x; sny[wv][pos] = y; snz[wv][pos] = z; }
        total += (int)__popcll(mask);
    }

    __syncthreads();   // neighbor LDS writes visible (cross-lane within wave)

    const float x = snx[wv][lane], y = sny[wv][lane], z = snz[wv][lane];

    // ---- layer 1: 3 -> 64 ----
    float h0[64];
#pragma unroll
    for (int j = 0; j < 64; ++j) {
        float a = fmaf(x, w0[j], fmaf(y, w0[64 + j], fmaf(z, w0[128 + j], b0[j])));
        h0[j] = fmaxf(a, 0.0f);
    }

    // ---- layer 2: 64 -> 64 ----
    float h1[64];
#pragma unroll
    for (int jb = 0; jb < 4; ++jb) {
        float acc[16];
#pragma unroll
        for (int i = 0; i < 16; ++i) acc[i] = b1[jb * 16 + i];
#pragma unroll
        for (int k = 0; k < 64; ++k) {
#pragma unroll
            for (int i = 0; i < 16; ++i)
                acc[i] = fmaf(h0[k], w1[k * 64 + jb * 16 + i], acc[i]);
        }
#pragma unroll
        for (int i = 0; i < 16; ++i) h1[jb * 16 + i] = fmaxf(acc[i], 0.0f);
    }

    // ---- layer 3: 64 -> 128, fused relu + neighbor max ----
#pragma unroll
    for (int jb = 0; jb < 8; ++jb) {
        float acc[16];
#pragma unroll
        for (int i = 0; i < 16; ++i) acc[i] = b2[jb * 16 + i];
#pragma unroll
        for (int k = 0; k < 64; ++k) {
#pragma unroll
            for (int i = 0; i < 16; ++i)
                acc[i] = fmaf(h1[k], w2[k * 128 + jb * 16 + i], acc[i]);
        }
#pragma unroll
        for (int i = 0; i < 16; ++i) {
            float v = fmaxf(acc[i], 0.0f);   // relu before pooling
            acc[i] = wave_fmax_nonneg(v);    // valid in lane 63
        }
        if (lane == 63) {
#pragma unroll
            for (int i = 0; i < 16; ++i) orow[3 + jb * 16 + i] = acc[i];
        }
    }
}

extern "C" void kernel_launch(void* const* d_in, const int* in_sizes, int n_in,
                              void* d_out, int out_size, void* d_ws, size_t ws_size,
                              hipStream_t stream)
{
    (void)in_sizes; (void)n_in; (void)out_size;
    const float* pts = (const float*)d_in[0];
    const float* w0  = (const float*)d_in[1];
    const float* b0  = (const float*)d_in[2];
    const float* w1  = (const float*)d_in[3];
    const float* b1  = (const float*)d_in[4];
    const float* w2  = (const float*)d_in[5];
    const float* b2  = (const float*)d_in[6];
    float* out = (float*)d_out;

    // Experiment first: writes only to d_ws, overwritten-irrelevant to output.
    if (ws_size >= BATCH * sizeof(unsigned long long)) {
        hipLaunchKernelGGL(fps_probe, dim3(BATCH), dim3(FPS_T), 0, stream,
                           pts, (unsigned long long*)d_ws);
    }
    hipLaunchKernelGGL(fps_kernel, dim3(BATCH), dim3(FPS_T), 0, stream, pts, out);
    hipLaunchKernelGGL(bqmlp_kernel, dim3(BATCH * KSAMP / 4), dim3(256), 0, stream,
                       pts, w0, b0, w1, b1, w2, b2, out);
}

// Round 6
// 793.373 us; speedup vs baseline: 2.3326x; 1.5762x over previous
//
#include <hip/hip_runtime.h>

#define BATCH 8
#define NPTS 4096
#define KSAMP 1024
#define KNEI 64
#define OUTC 131   // 3 xyz + 128 feat

typedef __attribute__((ext_vector_type(8))) short  bf16x8;
typedef __attribute__((ext_vector_type(4))) float  f32x4;

// ---------------------------------------------------------------------------
// bf16 split helpers (RNE via bit arithmetic; exact, no lib dependence).
// a ~= bf2f(hi) + bf2f(lo) with relative error ~2^-17.
// ---------------------------------------------------------------------------
__device__ __forceinline__ unsigned short f2bf_rne(float f)
{
    unsigned u = __float_as_uint(f);
    return (unsigned short)((u + 0x7FFFu + ((u >> 16) & 1u)) >> 16);
}
__device__ __forceinline__ float bf2f(unsigned short h)
{
    return __uint_as_float(((unsigned)h) << 16);
}

// ---------------------------------------------------------------------------
// DPP wave64 f32 max (verified R2+). Result valid in lane 63.
// ---------------------------------------------------------------------------
__device__ __forceinline__ unsigned long long umax64(unsigned long long a,
                                                     unsigned long long b)
{
    return a > b ? a : b;
}

#define DPP_U64_STEP(v, CTRL)                                                  \
    {                                                                          \
        int _lo = __builtin_amdgcn_update_dpp(0, (int)(unsigned)(v), (CTRL),   \
                                              0xF, 0xF, true);                 \
        int _hi = __builtin_amdgcn_update_dpp(0, (int)((v) >> 32), (CTRL),     \
                                              0xF, 0xF, true);                 \
        unsigned long long _o =                                                \
            ((unsigned long long)(unsigned)_hi << 32) | (unsigned)_lo;         \
        (v) = umax64((v), _o);                                                 \
    }

__device__ __forceinline__ unsigned long long wave_umax64(unsigned long long v)
{
    DPP_U64_STEP(v, 0x111)
    DPP_U64_STEP(v, 0x112)
    DPP_U64_STEP(v, 0x114)
    DPP_U64_STEP(v, 0x118)
    DPP_U64_STEP(v, 0x142)
    DPP_U64_STEP(v, 0x143)
    return v;
}

#define DPP_F32MAX_STEP(v, CTRL)                                               \
    {                                                                          \
        int _s = __builtin_amdgcn_update_dpp(0, __float_as_int(v), (CTRL),     \
                                             0xF, 0xF, true);                  \
        (v) = fmaxf((v), __int_as_float(_s));                                  \
    }

__device__ __forceinline__ float wave_fmax_nonneg(float v)
{
    DPP_F32MAX_STEP(v, 0x111)
    DPP_F32MAX_STEP(v, 0x112)
    DPP_F32MAX_STEP(v, 0x114)
    DPP_F32MAX_STEP(v, 0x118)
    DPP_F32MAX_STEP(v, 0x142)
    DPP_F32MAX_STEP(v, 0x143)
    return v;
}

// ---------------------------------------------------------------------------
// Kernel 1: FPS — VERBATIM the verified 628 us kernel (R2/R4). Untouched.
// ---------------------------------------------------------------------------
#define FPS_T 256
#define FPS_PPT 16

__global__ __launch_bounds__(FPS_T) void fps_kernel(const float* __restrict__ pts,
                                                    float* __restrict__ out)
{
    const int b = blockIdx.x;
    const int t = threadIdx.x;
    const float* p = pts + (size_t)b * NPTS * 3;

    __shared__ float lx[NPTS], ly[NPTS], lz[NPTS];
    __shared__ unsigned long long cand[2][4];

    float px[FPS_PPT], py[FPS_PPT], pz[FPS_PPT], md[FPS_PPT];
#pragma unroll
    for (int i = 0; i < FPS_PPT; ++i) {
        const int n = t * FPS_PPT + i;
        px[i] = p[n * 3 + 0];
        py[i] = p[n * 3 + 1];
        pz[i] = p[n * 3 + 2];
        lx[n] = px[i]; ly[n] = py[i]; lz[n] = pz[i];
        md[i] = 1e10f;
    }
    if (t == 0) {
        float* o = out + (size_t)b * KSAMP * OUTC;
        o[0] = p[0]; o[1] = p[1]; o[2] = p[2];
    }
    __syncthreads();

    const int wave = t >> 6;
    const int lane = t & 63;
    int cur = 0;

    for (int s = 1; s < KSAMP; ++s) {
        const float qx = lx[cur], qy = ly[cur], qz = lz[cur];

#pragma unroll
        for (int i = 0; i < FPS_PPT; ++i) {
            float dx = px[i] - qx, dy = py[i] - qy, dz = pz[i] - qz;
            float d = dx * dx + dy * dy + dz * dz;
            md[i] = fminf(md[i], d);
        }

        unsigned long long c[FPS_PPT];
#pragma unroll
        for (int i = 0; i < FPS_PPT; ++i)
            c[i] = ((unsigned long long)__float_as_uint(md[i]) << 32)
                 | (unsigned)(4095 - (t * FPS_PPT + i));
#pragma unroll
        for (int i = 0; i < 8; ++i) c[i] = umax64(c[i], c[i + 8]);
#pragma unroll
        for (int i = 0; i < 4; ++i) c[i] = umax64(c[i], c[i + 4]);
        c[0] = umax64(c[0], c[2]);
        c[1] = umax64(c[1], c[3]);
        unsigned long long best = umax64(c[0], c[1]);

        best = wave_umax64(best);
        const int par = s & 1;
        if (lane == 63) cand[par][wave] = best;
        __syncthreads();

        unsigned long long g = umax64(umax64(cand[par][0], cand[par][1]),
                                      umax64(cand[par][2], cand[par][3]));
        cur = 4095 - (int)(g & 0xffffffffu);

        if (t == 0) {
            float* o = out + ((size_t)b * KSAMP + s) * OUTC;
            o[0] = lx[cur]; o[1] = ly[cur]; o[2] = lz[cur];
        }
    }
}

// ---------------------------------------------------------------------------
// Weight prep: split w1/w2 into bf16 hi/lo and lay them out in MFMA B-frag
// order so bqmlp lanes read frags as single dwordx4 loads.
// B-frag layout for mfma_f32_16x16x32_bf16: lane holds B[k=8*(lane>>4)+i]
// [col=lane&15] for k-chunk kc (k += 32*kc), i=0..7.
// ws layout (ushort units): B1hi @0 (8 frags), B1lo @4096, B2hi @8192
// (16 frags), B2lo @16384. Total 24576 ushorts = 48 KB.
// ---------------------------------------------------------------------------
__global__ __launch_bounds__(256) void prep_kernel(const float* __restrict__ w1,
                                                   const float* __restrict__ w2,
                                                   unsigned short* __restrict__ ws)
{
    const int tid = blockIdx.x * 256 + threadIdx.x;
    if (tid >= 1536) return;
    const int fid  = tid >> 6;
    const int lane = tid & 63;
    const int lg = lane >> 4, lr = lane & 15;

    const float* W; int N, f; unsigned base_hi, base_lo;
    if (fid < 8) { W = w1; N = 64;  f = fid;     base_hi = 0;    base_lo = 4096; }
    else         { W = w2; N = 128; f = fid - 8; base_hi = 8192; base_lo = 16384; }
    const int nt = f >> 1, kc = f & 1;
    const int col = nt * 16 + lr;

    bf16x8 hi8, lo8;
#pragma unroll
    for (int i = 0; i < 8; ++i) {
        const int k = kc * 32 + lg * 8 + i;
        const float w = W[k * N + col];
        const unsigned short hs = f2bf_rne(w);
        hi8[i] = (short)hs;
        lo8[i] = (short)f2bf_rne(w - bf2f(hs));
    }
    ((bf16x8*)(ws + base_hi))[f * 64 + lane] = hi8;
    ((bf16x8*)(ws + base_lo))[f * 64 + lane] = lo8;
}

// ---------------------------------------------------------------------------
// Kernel 2 (MFMA): ball-query (verbatim numerics) + L1 fp32 (verbatim
// numerics) + L2/L3 via 3-pass bf16-split MFMA + fused relu/max-pool.
// One wave per query. h (h0 then h1) staged in LDS as bf16 hi/lo rows
// [64][72] (pad 8 to break bank alignment).
// ---------------------------------------------------------------------------
#define HPAD 72

__global__ __launch_bounds__(64) void bqmlp_mfma(
    const float* __restrict__ pts,
    const float* __restrict__ w0, const float* __restrict__ b0,
    const float* __restrict__ b1, const float* __restrict__ b2,
    const unsigned short* __restrict__ ws,
    float* __restrict__ out)
{
    const int q    = blockIdx.x;        // 0..8191
    const int bb   = q >> 10;
    const int lane = threadIdx.x;
    const int lg   = lane >> 4, lr = lane & 15;
    const float* p = pts + (size_t)bb * NPTS * 3;
    float* orow    = out + (size_t)q * OUTC;

    __shared__ unsigned short hb_hi[64 * HPAD];
    __shared__ unsigned short hb_lo[64 * HPAD];
    __shared__ float snx[KNEI], sny[KNEI], snz[KNEI];

    // ---- ball query (FROZEN numerics, verbatim from verified kernel) ----
    const float qx = orow[0], qy = orow[1], qz = orow[2];
    const float RR = 0.04f;
    const float q2 = __fadd_rn(__fadd_rn(__fmul_rn(qx, qx), __fmul_rn(qy, qy)),
                               __fmul_rn(qz, qz));

    snx[lane] = 0.0f; sny[lane] = 0.0f; snz[lane] = 0.0f;
    __syncthreads();

    int total = 0;
    for (int c = 0; c < NPTS / 64 && total < KNEI; ++c) {
        const int n = c * 64 + lane;
        const float x = p[n * 3 + 0];
        const float y = p[n * 3 + 1];
        const float z = p[n * 3 + 2];
        const float p2  = __fadd_rn(__fadd_rn(__fmul_rn(x, x), __fmul_rn(y, y)),
                                    __fmul_rn(z, z));
        const float dot = __fadd_rn(__fadd_rn(__fmul_rn(qx, x), __fmul_rn(qy, y)),
                                    __fmul_rn(qz, z));
        const float d2  = __fsub_rn(__fadd_rn(q2, p2), __fmul_rn(2.0f, dot));
        const bool valid = d2 < RR;
        const unsigned long long mask = __ballot(valid);
        const int pos = total + (int)__popcll(mask & ((1ull << lane) - 1ull));
        if (valid && pos < KNEI) { snx[pos] = x; sny[pos] = y; snz[pos] = z; }
        total += (int)__popcll(mask);
    }
    __syncthreads();

    const float x = snx[lane], y = sny[lane], z = snz[lane];

    // ---- layer 1: 3 -> 64, fp32 (verbatim numerics), lane = neighbor ----
    float h0[64];
#pragma unroll
    for (int j = 0; j < 64; ++j) {
        float a = fmaf(x, w0[j], fmaf(y, w0[64 + j], fmaf(z, w0[128 + j], b0[j])));
        h0[j] = fmaxf(a, 0.0f);
    }

    // ---- split h0 -> LDS bf16 hi/lo rows (lane = row) ----
#pragma unroll
    for (int c = 0; c < 8; ++c) {
        bf16x8 hi8, lo8;
#pragma unroll
        for (int i = 0; i < 8; ++i) {
            const float v = h0[c * 8 + i];
            const unsigned short hs = f2bf_rne(v);
            hi8[i] = (short)hs;
            lo8[i] = (short)f2bf_rne(v - bf2f(hs));
        }
        *(bf16x8*)&hb_hi[lane * HPAD + c * 8] = hi8;
        *(bf16x8*)&hb_lo[lane * HPAD + c * 8] = lo8;
    }
    __syncthreads();

    const bf16x8* B1h = (const bf16x8*)ws;          // entries [f*64+lane]
    const bf16x8* B1l = B1h + 512;
    const bf16x8* B2h = B1h + 1024;
    const bf16x8* B2l = B1h + 2048;

    // ---- layer 2: 64 -> 64 via MFMA (A = h0 frags from LDS) ----
    f32x4 acc2[4][4];
#pragma unroll
    for (int nt = 0; nt < 4; ++nt) {
        const float bv = b1[nt * 16 + lr];
#pragma unroll
        for (int mt = 0; mt < 4; ++mt)
            acc2[mt][nt] = (f32x4){bv, bv, bv, bv};
    }

#pragma unroll
    for (int mt = 0; mt < 4; ++mt) {
        bf16x8 ah[2], al[2];
#pragma unroll
        for (int kc = 0; kc < 2; ++kc) {
            ah[kc] = *(const bf16x8*)&hb_hi[(mt * 16 + lr) * HPAD + kc * 32 + lg * 8];
            al[kc] = *(const bf16x8*)&hb_lo[(mt * 16 + lr) * HPAD + kc * 32 + lg * 8];
        }
#pragma unroll
        for (int nt = 0; nt < 4; ++nt) {
#pragma unroll
            for (int kc = 0; kc < 2; ++kc) {
                const bf16x8 bh = B1h[(nt * 2 + kc) * 64 + lane];
                const bf16x8 bl = B1l[(nt * 2 + kc) * 64 + lane];
                acc2[mt][nt] = __builtin_amdgcn_mfma_f32_16x16x32_bf16(ah[kc], bh, acc2[mt][nt], 0, 0, 0);
                acc2[mt][nt] = __builtin_amdgcn_mfma_f32_16x16x32_bf16(ah[kc], bl, acc2[mt][nt], 0, 0, 0);
                acc2[mt][nt] = __builtin_amdgcn_mfma_f32_16x16x32_bf16(al[kc], bh, acc2[mt][nt], 0, 0, 0);
            }
        }
    }

    // ---- relu + split h1 -> LDS (C layout: row = mt*16 + 4*lg + r, col = nt*16+lr) ----
    __syncthreads();   // all A-frag reads of h0 done before overwrite
#pragma unroll
    for (int mt = 0; mt < 4; ++mt) {
#pragma unroll
        for (int nt = 0; nt < 4; ++nt) {
#pragma unroll
            for (int r = 0; r < 4; ++r) {
                const float v = fmaxf(acc2[mt][nt][r], 0.0f);
                const int row = mt * 16 + lg * 4 + r;
                const int col = nt * 16 + lr;
                const unsigned short hs = f2bf_rne(v);
                hb_hi[row * HPAD + col] = hs;
                hb_lo[row * HPAD + col] = f2bf_rne(v - bf2f(hs));
            }
        }
    }
    __syncthreads();

    // ---- layer 3: 64 -> 128 via MFMA, two nt-halves; fused relu+pool ----
#pragma unroll
    for (int h = 0; h < 2; ++h) {
        f32x4 acc3[4][4];
#pragma unroll
        for (int nt4 = 0; nt4 < 4; ++nt4) {
            const float bv = b2[(h * 4 + nt4) * 16 + lr];
#pragma unroll
            for (int mt = 0; mt < 4; ++mt)
                acc3[mt][nt4] = (f32x4){bv, bv, bv, bv};
        }

#pragma unroll
        for (int mt = 0; mt < 4; ++mt) {
            bf16x8 ah[2], al[2];
#pragma unroll
            for (int kc = 0; kc < 2; ++kc) {
                ah[kc] = *(const bf16x8*)&hb_hi[(mt * 16 + lr) * HPAD + kc * 32 + lg * 8];
                al[kc] = *(const bf16x8*)&hb_lo[(mt * 16 + lr) * HPAD + kc * 32 + lg * 8];
            }
#pragma unroll
            for (int nt4 = 0; nt4 < 4; ++nt4) {
                const int f = (h * 4 + nt4) * 2;
#pragma unroll
                for (int kc = 0; kc < 2; ++kc) {
                    const bf16x8 bh = B2h[(f + kc) * 64 + lane];
                    const bf16x8 bl = B2l[(f + kc) * 64 + lane];
                    acc3[mt][nt4] = __builtin_amdgcn_mfma_f32_16x16x32_bf16(ah[kc], bh, acc3[mt][nt4], 0, 0, 0);
                    acc3[mt][nt4] = __builtin_amdgcn_mfma_f32_16x16x32_bf16(ah[kc], bl, acc3[mt][nt4], 0, 0, 0);
                    acc3[mt][nt4] = __builtin_amdgcn_mfma_f32_16x16x32_bf16(al[kc], bh, acc3[mt][nt4], 0, 0, 0);
                }
            }
        }

        // relu + max over 64 neighbor rows: in-lane over (mt, r), then
        // cross-lane over the 4 lane-groups (xor 16, xor 32).
#pragma unroll
        for (int nt4 = 0; nt4 < 4; ++nt4) {
            float m = 0.0f;   // max(relu(.)) == relu(max(.)), identity 0 is exact
#pragma unroll
            for (int mt = 0; mt < 4; ++mt)
#pragma unroll
                for (int r = 0; r < 4; ++r)
                    m = fmaxf(m, acc3[mt][nt4][r]);
            m = fmaxf(m, __shfl_xor(m, 16));
            m = fmaxf(m, __shfl_xor(m, 32));
            if (lane < 16) orow[3 + (h * 4 + nt4) * 16 + lane] = m;
        }
    }
}

// ---------------------------------------------------------------------------
// Fallback fp32 MLP kernel (the R1/R2-verified 64-thread version), used only
// if ws_size is too small for the weight prep buffer.
// ---------------------------------------------------------------------------
__global__ __launch_bounds__(64) void bqmlp_fp32(
    const float* __restrict__ pts,
    const float* __restrict__ w0, const float* __restrict__ b0,
    const float* __restrict__ w1, const float* __restrict__ b1,
    const float* __restrict__ w2, const float* __restrict__ b2,
    float* __restrict__ out)
{
    const int q    = blockIdx.x;
    const int bb   = q >> 10;
    const int lane = threadIdx.x;
    const float* p = pts + (size_t)bb * NPTS * 3;
    float* orow    = out + (size_t)q * OUTC;

    const float qx = orow[0], qy = orow[1], qz = orow[2];
    const float RR = 0.04f;
    const float q2 = __fadd_rn(__fadd_rn(__fmul_rn(qx, qx), __fmul_rn(qy, qy)),
                               __fmul_rn(qz, qz));

    __shared__ float nx[KNEI], ny[KNEI], nz[KNEI];
    nx[lane] = 0.0f; ny[lane] = 0.0f; nz[lane] = 0.0f;
    __syncthreads();

    int total = 0;
    for (int c = 0; c < NPTS / 64 && total < KNEI; ++c) {
        const int n = c * 64 + lane;
        const float x = p[n * 3 + 0];
        const float y = p[n * 3 + 1];
        const float z = p[n * 3 + 2];
        const float p2  = __fadd_rn(__fadd_rn(__fmul_rn(x, x), __fmul_rn(y, y)),
                                    __fmul_rn(z, z));
        const float dot = __fadd_rn(__fadd_rn(__fmul_rn(qx, x), __fmul_rn(qy, y)),
                                    __fmul_rn(qz, z));
        const float d2  = __fsub_rn(__fadd_rn(q2, p2), __fmul_rn(2.0f, dot));
        const bool valid = d2 < RR;
        const unsigned long long mask = __ballot(valid);
        const int pos = total + (int)__popcll(mask & ((1ull << lane) - 1ull));
        if (valid && pos < KNEI) { nx[pos] = x; ny[pos] = y; nz[pos] = z; }
        total += (int)__popcll(mask);
    }
    __syncthreads();

    const float x = nx[lane], y = ny[lane], z = nz[lane];

    float h0[64];
#pragma unroll
    for (int j = 0; j < 64; ++j) {
        float a = fmaf(x, w0[j], fmaf(y, w0[64 + j], fmaf(z, w0[128 + j], b0[j])));
        h0[j] = fmaxf(a, 0.0f);
    }

    float h1[64];
#pragma unroll
    for (int jb = 0; jb < 4; ++jb) {
        float acc[16];
#pragma unroll
        for (int i = 0; i < 16; ++i) acc[i] = b1[jb * 16 + i];
#pragma unroll
        for (int k = 0; k < 64; ++k) {
#pragma unroll
            for (int i = 0; i < 16; ++i)
                acc[i] = fmaf(h0[k], w1[k * 64 + jb * 16 + i], acc[i]);
        }
#pragma unroll
        for (int i = 0; i < 16; ++i) h1[jb * 16 + i] = fmaxf(acc[i], 0.0f);
    }

#pragma unroll
    for (int jb = 0; jb < 8; ++jb) {
        float acc[16];
#pragma unroll
        for (int i = 0; i < 16; ++i) acc[i] = b2[jb * 16 + i];
#pragma unroll
        for (int k = 0; k < 64; ++k) {
#pragma unroll
            for (int i = 0; i < 16; ++i)
                acc[i] = fmaf(h1[k], w2[k * 128 + jb * 16 + i], acc[i]);
        }
#pragma unroll
        for (int i = 0; i < 16; ++i) {
            float v = fmaxf(acc[i], 0.0f);
            acc[i] = wave_fmax_nonneg(v);
        }
        if (lane == 63) {
#pragma unroll
            for (int i = 0; i < 16; ++i) orow[3 + jb * 16 + i] = acc[i];
        }
    }
}

extern "C" void kernel_launch(void* const* d_in, const int* in_sizes, int n_in,
                              void* d_out, int out_size, void* d_ws, size_t ws_size,
                              hipStream_t stream)
{
    (void)in_sizes; (void)n_in; (void)out_size;
    const float* pts = (const float*)d_in[0];
    const float* w0  = (const float*)d_in[1];
    const float* b0  = (const float*)d_in[2];
    const float* w1  = (const float*)d_in[3];
    const float* b1  = (const float*)d_in[4];
    const float* w2  = (const float*)d_in[5];
    const float* b2  = (const float*)d_in[6];
    float* out = (float*)d_out;

    hipLaunchKernelGGL(fps_kernel, dim3(BATCH), dim3(FPS_T), 0, stream, pts, out);

    if (ws_size >= 49152) {
        unsigned short* wsp = (unsigned short*)d_ws;
        hipLaunchKernelGGL(prep_kernel, dim3(6), dim3(256), 0, stream, w1, w2, wsp);
        hipLaunchKernelGGL(bqmlp_mfma, dim3(BATCH * KSAMP), dim3(64), 0, stream,
                           pts, w0, b0, b1, b2, wsp, out);
    } else {
        hipLaunchKernelGGL(bqmlp_fp32, dim3(BATCH * KSAMP), dim3(64), 0, stream,
                           pts, w0, b0, w1, b1, w2, b2, out);
    }
}